// Round 8
// baseline (313.594 us; speedup 1.0000x reference)
//
#include <hip/hip_runtime.h>
#include <stdint.h>

#define EMB_DIM 192
#define CDIM 32
#define TDIM 4
#define N_Y 50000
#define N_X 32768
#define KNBR 8
#define ECNT (N_X*KNBR)  // 262144
#define NTILE 4096       // ECNT/64
#define NBLK 768         // persistent: 3 blocks/CU x 256 CU

// LDS row strides (shorts), odd-word -> low conflicts (proven R3-R5)
#define H1S 134
#define H2S 262
#define KS  33
#define ES  200

// prep_all block ranges
#define PREP_TW 272                 // 69632 w1/w2/w3 transpose elems / 256
#define PREP_Y0 PREP_TW
#define PREP_X0 (PREP_TW + 782)
#define PREP_NB (PREP_TW + 782 + 512)

typedef __attribute__((ext_vector_type(8))) short bf16x8;
typedef __attribute__((ext_vector_type(4))) float f32x4;

static __device__ __forceinline__ short f2bf(float f){
  unsigned u = __float_as_uint(f);
  return (short)((u + 0x7FFFu) >> 16);
}
static __device__ __forceinline__ unsigned pk_bf16(float lo, float hi){
  return ((__float_as_uint(lo) + 0x7FFFu) >> 16) |
         ((((__float_as_uint(hi) + 0x7FFFu) >> 16)) << 16);
}
static __device__ __forceinline__ float geluf(float x){
  float x2 = x * x;
  float u  = __builtin_fmaf(0.044715f, x2, 1.0f);
  float p  = x * -1.5957691216057308f;      // -2*0.7978845608
  float e  = __expf(p * u);                 // exp(-2t)
  return x * __builtin_amdgcn_rcpf(1.0f + e);
}
// LDS-only barrier: lgkmcnt(0)+s_barrier WITHOUT vmcnt drain -> register
// prefetches (global loads) stay in flight across fences. All intra-block
// producer->consumer paths in fused_edge are ds_write -> ds_read.
static __device__ __forceinline__ void barrier_lds(){
  asm volatile("s_waitcnt lgkmcnt(0)\n\ts_barrier" ::: "memory");
}

// ---- ONE prep kernel: [0,272) transpose w1/w2/w3; [272,1566) precompute c ----
// precompute reads W0 DIRECTLY (native (K,N) layout): B-frag lanes are
// n-consecutive -> coalesced dword loads; no w0t dependency, no extra launch.
__global__ __launch_bounds__(256, 2) void prep_all(
    const float* __restrict__ ypts, const float* __restrict__ xpts,
    const float* __restrict__ W0, const float* __restrict__ b0,
    const float* __restrict__ W1, const float* __restrict__ W2,
    const float* __restrict__ W3,
    short* __restrict__ w1t, short* __restrict__ w2t, short* __restrict__ w3t,
    short* __restrict__ c_y, float* __restrict__ c_x)
{
  const int tid = threadIdx.x;
  if (blockIdx.x < PREP_TW) {
    int id = blockIdx.x * 256 + tid;
    if (id < 32768) {                     // w1t[n*128+k] = W1[k][n] (128x256)
      int n = id >> 7, k = id & 127;
      w1t[id] = f2bf(W1[k * 256 + n]);
    } else if (id < 65536) {              // w2t[n*256+k] = W2[k][n] (256x128)
      int loc = id - 32768; int n = loc >> 8, k = loc & 255;
      w2t[loc] = f2bf(W2[k * 128 + n]);
    } else if (id < 69632) {              // w3t[n*128+k] = W3[k][n] (128x32)
      int loc = id - 65536; int n = loc >> 7, k = loc & 127;
      w3t[loc] = f2bf(W3[k * 32 + n]);
    }
    return;
  }

  __shared__ __attribute__((aligned(16))) short s_e[64 * ES];
  const bool isY = blockIdx.x < PREP_X0;
  const int row0 = isY ? (blockIdx.x - PREP_Y0) * 64 : (blockIdx.x - PREP_X0) * 64;
  const int wave = tid >> 6, lane = tid & 63;
  const int quad = lane >> 4, l15 = lane & 15;
  const float* W0h = W0 + (isY ? 0 : 192 * 128);

  // ---- B-frags direct from W0 (96 coalesced dword loads/thread) ----
  short bv[2][48];
  #pragma unroll
  for (int nt = 0; nt < 2; ++nt) {
    int n = wave * 32 + nt * 16 + l15;
    #pragma unroll
    for (int ch = 0; ch < 6; ++ch)
      #pragma unroll
      for (int j = 0; j < 8; ++j)
        bv[nt][ch * 8 + j] = f2bf(W0h[(size_t)(ch * 32 + quad * 8 + j) * 128 + n]);
  }

  // ---- embed phase: thread (r,q) computes 24 (d,i) pairs ----
  {
    const int r = tid >> 2, q = tid & 3;
    const int grow = row0 + r;
    const bool valid = isY ? (grow < N_Y) : true;
    const float* src = isY ? (ypts + (size_t)grow * 3) : (xpts + (size_t)grow * 3);
    float c[3] = {0.f, 0.f, 0.f};
    if (valid) { c[0] = src[0]; c[1] = src[1]; c[2] = src[2]; }
    #pragma unroll
    for (int j = 0; j < 24; ++j) {
      int p = q * 24 + j;
      int d = p >> 5, i = p & 31;
      float f = __expf(-0.28782313662425575f * (float)i);   // (1e-4)^(i/32)
      float s, co;
      __sincosf(c[d] * f, &s, &co);
      *(unsigned*)&s_e[r * ES + d * 64 + 2 * i] = pk_bf16(s, co);
    }
  }
  __syncthreads();

  f32x4 acc[4][2];
  #pragma unroll
  for (int mt = 0; mt < 4; ++mt)
    #pragma unroll
    for (int nt = 0; nt < 2; ++nt) acc[mt][nt] = (f32x4){0.f, 0.f, 0.f, 0.f};
  #pragma unroll
  for (int ch = 0; ch < 6; ++ch) {
    bf16x8 a[4];
    #pragma unroll
    for (int mt = 0; mt < 4; ++mt)
      a[mt] = *(const bf16x8*)&s_e[(mt * 16 + l15) * ES + ch * 32 + quad * 8];
    #pragma unroll
    for (int mt = 0; mt < 4; ++mt)
      #pragma unroll
      for (int nt = 0; nt < 2; ++nt)
        acc[mt][nt] = __builtin_amdgcn_mfma_f32_16x16x32_bf16(
            a[mt], *(const bf16x8*)&bv[nt][ch * 8], acc[mt][nt], 0, 0, 0);
  }
  #pragma unroll
  for (int nt = 0; nt < 2; ++nt) {
    int col = wave * 32 + nt * 16 + l15;
    float bias = isY ? 0.f : b0[col];
    #pragma unroll
    for (int mt = 0; mt < 4; ++mt)
      #pragma unroll
      for (int rg = 0; rg < 4; ++rg) {
        int grow = row0 + mt * 16 + quad * 4 + rg;
        if (isY) { if (grow < N_Y) c_y[(size_t)grow * 128 + col] = f2bf(acc[mt][nt][rg]); }
        else     { c_x[(size_t)grow * 128 + col] = acc[mt][nt][rg] + bias; }
      }
  }
}

// ---- persistent edge kernel: R5 layer structure + c_y prefetch + lgkm barriers ----
// region1 [0,33536): h2 (64xH2S bf16), later kern (64xKS f32)
// region2 [33536,50688): h1 (64xH1S bf16), later h3
__global__ __launch_bounds__(256, 3) void fused_edge(
    const short* __restrict__ c_y, const float* __restrict__ c_x,
    const int* __restrict__ nidx, const float* __restrict__ f_y,
    const short* __restrict__ w1t, const float* __restrict__ b1,
    const short* __restrict__ w2t, const float* __restrict__ b2,
    const short* __restrict__ w3t, const float* __restrict__ b3,
    float* __restrict__ out)
{
  __shared__ __attribute__((aligned(16))) char smem[50688];
  short* s_h2   = (short*)smem;
  float* s_kern = (float*)smem;
  short* s_h1   = (short*)(smem + 33536);

  const int tid  = threadIdx.x;
  const int wave = tid >> 6, lane = tid & 63;
  const int quad = lane >> 4, l15 = lane & 15;
  const int r    = tid >> 2, q = tid & 3;      // phase-0 mapping
  const int xloc = tid >> 5, cc = tid & 31;    // reduce mapping

  // prefetch pipeline: c_y data 1 tile ahead, nidx 2 tiles ahead (16+1 regs)
  int   pf_idx1;
  uint4 pf_cy[4];
  {
    int idx0 = nidx[blockIdx.x * 64 + r];
    const uint4* cyp = (const uint4*)(c_y + (size_t)idx0 * 128 + q * 32);
    #pragma unroll
    for (int i = 0; i < 4; ++i) pf_cy[i] = cyp[i];
    int t1 = blockIdx.x + NBLK; if (t1 >= NTILE) t1 = blockIdx.x;
    pf_idx1 = nidx[t1 * 64 + r];
  }

  for (int tile = blockIdx.x; tile < NTILE; tile += NBLK) {
    const int e0 = tile * 64;

    // ---- phase 0: h1 = gelu(c_y[idx] + c_x[e>>3]); c_y from prefetch regs ----
    {
      float4 cxv[8];
      const float4* cxp = (const float4*)(c_x + (size_t)((e0 + r) >> 3) * 128 + q * 32);
      #pragma unroll
      for (int i = 0; i < 8; ++i) cxv[i] = cxp[i];
      const float* cxa = (const float*)cxv;
      const unsigned* cya = (const unsigned*)pf_cy;
      unsigned pk[16];
      #pragma unroll
      for (int jj = 0; jj < 16; ++jj) {
        unsigned u = cya[jj];
        float lo = __uint_as_float(u << 16)         + cxa[2 * jj];
        float hi = __uint_as_float(u & 0xffff0000u) + cxa[2 * jj + 1];
        pk[jj] = pk_bf16(geluf(lo), geluf(hi));
      }
      uint4* dst = (uint4*)&s_h1[r * H1S + q * 32];
      #pragma unroll
      for (int jj = 0; jj < 4; ++jj)
        dst[jj] = *(uint4*)&pk[jj * 4];
    }
    // issue NEXT tile's c_y gather (4 barriers of coverage) + idx for tile+2
    {
      const uint4* cyp = (const uint4*)(c_y + (size_t)pf_idx1 * 128 + q * 32);
      #pragma unroll
      for (int i = 0; i < 4; ++i) pf_cy[i] = cyp[i];
      int t2 = tile + 2 * NBLK; if (t2 >= NTILE) t2 = tile;
      pf_idx1 = nidx[t2 * 64 + r];
    }
    barrier_lds();   // h1 visible; prior tile's s_kern reads done

    // ---------- layer 1: 128 -> 256, GELU (wave owns 64 cols) ----------
    {
      f32x4 acc1[4][4];
      #pragma unroll
      for (int mt = 0; mt < 4; ++mt)
        #pragma unroll
        for (int nt = 0; nt < 4; ++nt) acc1[mt][nt] = (f32x4){0.f, 0.f, 0.f, 0.f};
      #pragma unroll
      for (int ch = 0; ch < 4; ++ch) {
        bf16x8 a[4], b[4];
        #pragma unroll
        for (int mt = 0; mt < 4; ++mt)
          a[mt] = *(const bf16x8*)&s_h1[(mt * 16 + l15) * H1S + ch * 32 + quad * 8];
        #pragma unroll
        for (int nt = 0; nt < 4; ++nt)
          b[nt] = *(const bf16x8*)&w1t[(size_t)(wave * 64 + nt * 16 + l15) * 128 + ch * 32 + quad * 8];
        #pragma unroll
        for (int mt = 0; mt < 4; ++mt)
          #pragma unroll
          for (int nt = 0; nt < 4; ++nt)
            acc1[mt][nt] = __builtin_amdgcn_mfma_f32_16x16x32_bf16(a[mt], b[nt], acc1[mt][nt], 0, 0, 0);
      }
      #pragma unroll
      for (int nt = 0; nt < 4; ++nt) {
        int col = wave * 64 + nt * 16 + l15;
        float bias = b1[col];
        #pragma unroll
        for (int mt = 0; mt < 4; ++mt)
          #pragma unroll
          for (int rg = 0; rg < 4; ++rg) {
            int row = mt * 16 + quad * 4 + rg;
            s_h2[row * H2S + col] = f2bf(geluf(acc1[mt][nt][rg] + bias));
          }
      }
    }
    barrier_lds();   // h2 visible; h1 reads done -> h3 may overwrite region2

    // ---------- layer 2: 256 -> 128, GELU (wave owns 32 cols) ----------
    {
      f32x4 acc2[4][2];
      #pragma unroll
      for (int mt = 0; mt < 4; ++mt)
        #pragma unroll
        for (int nt = 0; nt < 2; ++nt) acc2[mt][nt] = (f32x4){0.f, 0.f, 0.f, 0.f};
      #pragma unroll
      for (int ch = 0; ch < 8; ++ch) {
        bf16x8 a[4], b[2];
        #pragma unroll
        for (int mt = 0; mt < 4; ++mt)
          a[mt] = *(const bf16x8*)&s_h2[(mt * 16 + l15) * H2S + ch * 32 + quad * 8];
        #pragma unroll
        for (int nt = 0; nt < 2; ++nt)
          b[nt] = *(const bf16x8*)&w2t[(size_t)(wave * 32 + nt * 16 + l15) * 256 + ch * 32 + quad * 8];
        #pragma unroll
        for (int mt = 0; mt < 4; ++mt)
          #pragma unroll
          for (int nt = 0; nt < 2; ++nt)
            acc2[mt][nt] = __builtin_amdgcn_mfma_f32_16x16x32_bf16(a[mt], b[nt], acc2[mt][nt], 0, 0, 0);
      }
      #pragma unroll
      for (int nt = 0; nt < 2; ++nt) {
        int col = wave * 32 + nt * 16 + l15;
        float bias = b2[col];
        #pragma unroll
        for (int mt = 0; mt < 4; ++mt)
          #pragma unroll
          for (int rg = 0; rg < 4; ++rg) {
            int row = mt * 16 + quad * 4 + rg;
            s_h1[row * H1S + col] = f2bf(geluf(acc2[mt][nt][rg] + bias));   // h3
          }
      }
    }
    barrier_lds();   // h3 visible; h2 reads done -> kern may overwrite region1

    // ---------- layer 3: 128 -> 32 linear (wave owns 16 rows) -> s_kern ----------
    {
      f32x4 acc3[2];
      acc3[0] = (f32x4){0.f, 0.f, 0.f, 0.f};
      acc3[1] = (f32x4){0.f, 0.f, 0.f, 0.f};
      #pragma unroll
      for (int ch = 0; ch < 4; ++ch) {
        bf16x8 a3 = *(const bf16x8*)&s_h1[(wave * 16 + l15) * H1S + ch * 32 + quad * 8];
        #pragma unroll
        for (int nt = 0; nt < 2; ++nt) {
          bf16x8 b3f = *(const bf16x8*)&w3t[(size_t)(nt * 16 + l15) * 128 + ch * 32 + quad * 8];
          acc3[nt] = __builtin_amdgcn_mfma_f32_16x16x32_bf16(a3, b3f, acc3[nt], 0, 0, 0);
        }
      }
      #pragma unroll
      for (int nt = 0; nt < 2; ++nt) {
        int col = nt * 16 + l15;
        float bias = b3[col];
        #pragma unroll
        for (int rg = 0; rg < 4; ++rg) {
          int row = wave * 16 + quad * 4 + rg;
          s_kern[row * KS + col] = acc3[nt][rg] + bias;
        }
      }
    }
    barrier_lds();   // kern visible; h3 reads done -> next phase0 may write region2

    // ---------- fused reduce (f_y inline, R5-style: no long-lived regs) ----------
    {
      float acc[TDIM] = {0.f, 0.f, 0.f, 0.f};
      const int ebase = xloc * 8;
      #pragma unroll
      for (int j = 0; j < KNBR; ++j) {
        float kv = s_kern[(ebase + j) * KS + cc];
        int idx = nidx[e0 + ebase + j];
        const float* fp = f_y + (size_t)idx * CDIM + cc;
        #pragma unroll
        for (int t = 0; t < TDIM; ++t)
          acc[t] += kv * fp[(size_t)t * N_Y * CDIM];
      }
      const int xg = tile * 8 + xloc;
      #pragma unroll
      for (int t = 0; t < TDIM; ++t)
        out[((size_t)t * N_X + xg) * CDIM + cc] = acc[t];
    }
  }
}

extern "C" void kernel_launch(void* const* d_in, const int* in_sizes, int n_in,
                              void* d_out, int out_size, void* d_ws, size_t ws_size,
                              hipStream_t stream)
{
  const float* y   = (const float*)d_in[0];
  const float* x   = (const float*)d_in[1];
  const float* f_y = (const float*)d_in[2];
  const int*  nidx = (const int*)d_in[3];
  const float* W0 = (const float*)d_in[4];  const float* b0 = (const float*)d_in[5];
  const float* W1 = (const float*)d_in[6];  const float* b1 = (const float*)d_in[7];
  const float* W2 = (const float*)d_in[8];  const float* b2 = (const float*)d_in[9];
  const float* W3 = (const float*)d_in[10]; const float* b3 = (const float*)d_in[11];

  char* ws = (char*)d_ws;
  short* c_y  = (short*)(ws + 0);           // 50000*128*2  = 12,800,000
  float* c_x  = (float*)(ws + 12800000);    // 32768*128*4  = 16,777,216
  short* w1t  = (short*)(ws + 29577216);    // 256*128*2
  short* w2t  = (short*)(ws + 29642752);    // 128*256*2
  short* w3t  = (short*)(ws + 29708288);    //  32*128*2

  hipLaunchKernelGGL(prep_all, dim3(PREP_NB), dim3(256), 0, stream,
                     y, x, W0, b0, W1, W2, W3, w1t, w2t, w3t, c_y, c_x);
  hipLaunchKernelGGL(fused_edge, dim3(NBLK), dim3(256), 0, stream,
                     c_y, c_x, nidx, f_y, w1t, b1, w2t, b2, w3t, b3, (float*)d_out);
}

// Round 9
// 240.899 us; speedup vs baseline: 1.3018x; 1.3018x over previous
//
#include <hip/hip_runtime.h>
#include <stdint.h>

#define EMB_DIM 192
#define CDIM 32
#define TDIM 4
#define N_Y 50000
#define N_X 32768
#define KNBR 8
#define ECNT (N_X*KNBR)  // 262144

// LDS row strides (shorts), odd-word -> low conflicts (proven R3-R5)
#define H1S 134
#define H2S 262
#define KS  33
#define ES  200

// prep_all block ranges
#define PREP_TW 272                 // 69632 w1/w2/w3 transpose elems / 256
#define PREP_Y0 PREP_TW
#define PREP_X0 (PREP_TW + 782)
#define PREP_NB (PREP_TW + 782 + 512)

typedef __attribute__((ext_vector_type(8))) short bf16x8;
typedef __attribute__((ext_vector_type(4))) float f32x4;

static __device__ __forceinline__ short f2bf(float f){
  unsigned u = __float_as_uint(f);
  return (short)((u + 0x7FFFu) >> 16);
}
static __device__ __forceinline__ unsigned pk_bf16(float lo, float hi){
  return ((__float_as_uint(lo) + 0x7FFFu) >> 16) |
         ((((__float_as_uint(hi) + 0x7FFFu) >> 16)) << 16);
}
static __device__ __forceinline__ float geluf(float x){
  float x2 = x * x;
  float u  = __builtin_fmaf(0.044715f, x2, 1.0f);
  float p  = x * -1.5957691216057308f;      // -2*0.7978845608
  float e  = __expf(p * u);                 // exp(-2t)
  return x * __builtin_amdgcn_rcpf(1.0f + e);
}

// ---- ONE prep kernel: [0,272) transpose w1/w2/w3; [272,1566) precompute c ----
// Embedding trig via NATIVE v_sin/v_cos (input in revolutions): our angles are
// p*f in [0,1] rad -> rev in [0,0.16], no range reduction needed. This replaces
// ocml __sincosf (~40-60 ops w/ Payne-Hanek) with ~6 ops per (sin,cos) pair.
__global__ __launch_bounds__(256, 2) void prep_all(
    const float* __restrict__ ypts, const float* __restrict__ xpts,
    const float* __restrict__ W0, const float* __restrict__ b0,
    const float* __restrict__ W1, const float* __restrict__ W2,
    const float* __restrict__ W3,
    short* __restrict__ w1t, short* __restrict__ w2t, short* __restrict__ w3t,
    short* __restrict__ c_y, float* __restrict__ c_x)
{
  const int tid = threadIdx.x;
  if (blockIdx.x < PREP_TW) {
    int id = blockIdx.x * 256 + tid;
    if (id < 32768) {                     // w1t[n*128+k] = W1[k][n] (128x256)
      int n = id >> 7, k = id & 127;
      w1t[id] = f2bf(W1[k * 256 + n]);
    } else if (id < 65536) {              // w2t[n*256+k] = W2[k][n] (256x128)
      int loc = id - 32768; int n = loc >> 8, k = loc & 255;
      w2t[loc] = f2bf(W2[k * 128 + n]);
    } else if (id < 69632) {              // w3t[n*128+k] = W3[k][n] (128x32)
      int loc = id - 65536; int n = loc >> 7, k = loc & 127;
      w3t[loc] = f2bf(W3[k * 32 + n]);
    }
    return;
  }

  __shared__ __attribute__((aligned(16))) short s_e[64 * ES];
  const bool isY = blockIdx.x < PREP_X0;
  const int row0 = isY ? (blockIdx.x - PREP_Y0) * 64 : (blockIdx.x - PREP_X0) * 64;
  const int wave = tid >> 6, lane = tid & 63;
  const int quad = lane >> 4, l15 = lane & 15;
  const float* W0h = W0 + (isY ? 0 : 192 * 128);

  // ---- B-frags direct from W0 (coalesced dword loads; no w0t staging) ----
  short bv[2][48];
  #pragma unroll
  for (int nt = 0; nt < 2; ++nt) {
    int n = wave * 32 + nt * 16 + l15;
    #pragma unroll
    for (int ch = 0; ch < 6; ++ch)
      #pragma unroll
      for (int j = 0; j < 8; ++j)
        bv[nt][ch * 8 + j] = f2bf(W0h[(size_t)(ch * 32 + quad * 8 + j) * 128 + n]);
  }

  // ---- embed phase: thread (r,q) computes 24 (d,i) pairs, native trig ----
  {
    const int r = tid >> 2, q = tid & 3;
    const int grow = row0 + r;
    const bool valid = isY ? (grow < N_Y) : true;
    const float* src = isY ? (ypts + (size_t)grow * 3) : (xpts + (size_t)grow * 3);
    float c[3] = {0.f, 0.f, 0.f};
    if (valid) { c[0] = src[0]; c[1] = src[1]; c[2] = src[2]; }
    #pragma unroll
    for (int j = 0; j < 24; ++j) {
      int p = q * 24 + j;
      int d = p >> 5, i = p & 31;
      // f_i = (1e-4)^(i/32); rev = p*f/(2pi)
      float f = __expf(-0.28782313662425575f * (float)i);
      float rev = c[d] * f * 0.15915494309189535f;
      float s  = __builtin_amdgcn_sinf(rev);    // v_sin_f32: sin(rev*2pi)
      float co = __builtin_amdgcn_cosf(rev);    // v_cos_f32
      *(unsigned*)&s_e[r * ES + d * 64 + 2 * i] = pk_bf16(s, co);
    }
  }
  __syncthreads();

  f32x4 acc[4][2];
  #pragma unroll
  for (int mt = 0; mt < 4; ++mt)
    #pragma unroll
    for (int nt = 0; nt < 2; ++nt) acc[mt][nt] = (f32x4){0.f, 0.f, 0.f, 0.f};
  #pragma unroll
  for (int ch = 0; ch < 6; ++ch) {
    bf16x8 a[4];
    #pragma unroll
    for (int mt = 0; mt < 4; ++mt)
      a[mt] = *(const bf16x8*)&s_e[(mt * 16 + l15) * ES + ch * 32 + quad * 8];
    #pragma unroll
    for (int mt = 0; mt < 4; ++mt)
      #pragma unroll
      for (int nt = 0; nt < 2; ++nt)
        acc[mt][nt] = __builtin_amdgcn_mfma_f32_16x16x32_bf16(
            a[mt], *(const bf16x8*)&bv[nt][ch * 8], acc[mt][nt], 0, 0, 0);
  }
  #pragma unroll
  for (int nt = 0; nt < 2; ++nt) {
    int col = wave * 32 + nt * 16 + l15;
    float bias = isY ? 0.f : b0[col];
    #pragma unroll
    for (int mt = 0; mt < 4; ++mt)
      #pragma unroll
      for (int rg = 0; rg < 4; ++rg) {
        int grow = row0 + mt * 16 + quad * 4 + rg;
        if (isY) { if (grow < N_Y) c_y[(size_t)grow * 128 + col] = f2bf(acc[mt][nt][rg]); }
        else     { c_x[(size_t)grow * 128 + col] = acc[mt][nt][rg] + bias; }
      }
  }
}

// ---- edge kernel: EXACT R5 structure (proven 146 us, no spills) ----
// region1 [0,33536): h2 (64xH2S bf16), later kern (64xKS f32)
// region2 [33536,50688): h1 (64xH1S bf16), later h3
__global__ __launch_bounds__(256, 3) void fused_edge(
    const short* __restrict__ c_y, const float* __restrict__ c_x,
    const int* __restrict__ nidx, const float* __restrict__ f_y,
    const short* __restrict__ w1t, const float* __restrict__ b1,
    const short* __restrict__ w2t, const float* __restrict__ b2,
    const short* __restrict__ w3t, const float* __restrict__ b3,
    float* __restrict__ out)
{
  __shared__ __attribute__((aligned(16))) char smem[50688];
  short* s_h2   = (short*)smem;
  float* s_kern = (float*)smem;
  short* s_h1   = (short*)(smem + 33536);

  const int tid  = threadIdx.x;
  const int e0   = blockIdx.x * 64;
  const int wave = tid >> 6, lane = tid & 63;
  const int quad = lane >> 4, l15 = lane & 15;

  // ---- phase 0: h1 = gelu(c_y[idx] + c_x[e>>3]) ----
  {
    const int r = tid >> 2, q = tid & 3;
    const int idx = nidx[e0 + r];
    const uint4*  cyp = (const uint4*)(c_y + (size_t)idx * 128 + q * 32);
    const float4* cxp = (const float4*)(c_x + (size_t)((e0 + r) >> 3) * 128 + q * 32);
    uint4  cyv[4];
    float4 cxv[8];
    #pragma unroll
    for (int i = 0; i < 4; ++i) cyv[i] = cyp[i];
    #pragma unroll
    for (int i = 0; i < 8; ++i) cxv[i] = cxp[i];
    const float* cxa = (const float*)cxv;
    const unsigned* cya = (const unsigned*)cyv;
    unsigned pk[16];
    #pragma unroll
    for (int jj = 0; jj < 16; ++jj) {
      unsigned u = cya[jj];
      float lo = __uint_as_float(u << 16)         + cxa[2 * jj];
      float hi = __uint_as_float(u & 0xffff0000u) + cxa[2 * jj + 1];
      pk[jj] = pk_bf16(geluf(lo), geluf(hi));
    }
    uint4* dst = (uint4*)&s_h1[r * H1S + q * 32];
    #pragma unroll
    for (int jj = 0; jj < 4; ++jj)
      dst[jj] = *(uint4*)&pk[jj * 4];
  }
  __syncthreads();

  // ---------- layer 1: 128 -> 256, GELU (wave owns 64 cols) ----------
  {
    f32x4 acc1[4][4];
    #pragma unroll
    for (int mt = 0; mt < 4; ++mt)
      #pragma unroll
      for (int nt = 0; nt < 4; ++nt) acc1[mt][nt] = (f32x4){0.f, 0.f, 0.f, 0.f};
    #pragma unroll
    for (int ch = 0; ch < 4; ++ch) {
      bf16x8 a[4], b[4];
      #pragma unroll
      for (int mt = 0; mt < 4; ++mt)
        a[mt] = *(const bf16x8*)&s_h1[(mt * 16 + l15) * H1S + ch * 32 + quad * 8];
      #pragma unroll
      for (int nt = 0; nt < 4; ++nt)
        b[nt] = *(const bf16x8*)&w1t[(size_t)(wave * 64 + nt * 16 + l15) * 128 + ch * 32 + quad * 8];
      #pragma unroll
      for (int mt = 0; mt < 4; ++mt)
        #pragma unroll
        for (int nt = 0; nt < 4; ++nt)
          acc1[mt][nt] = __builtin_amdgcn_mfma_f32_16x16x32_bf16(a[mt], b[nt], acc1[mt][nt], 0, 0, 0);
    }
    #pragma unroll
    for (int nt = 0; nt < 4; ++nt) {
      int col = wave * 64 + nt * 16 + l15;
      float bias = b1[col];
      #pragma unroll
      for (int mt = 0; mt < 4; ++mt)
        #pragma unroll
        for (int rg = 0; rg < 4; ++rg) {
          int row = mt * 16 + quad * 4 + rg;
          s_h2[row * H2S + col] = f2bf(geluf(acc1[mt][nt][rg] + bias));
        }
    }
  }
  __syncthreads();   // h2 visible; h1 reads done -> h3 may overwrite region2

  // ---------- layer 2: 256 -> 128, GELU (wave owns 32 cols) ----------
  {
    f32x4 acc2[4][2];
    #pragma unroll
    for (int mt = 0; mt < 4; ++mt)
      #pragma unroll
      for (int nt = 0; nt < 2; ++nt) acc2[mt][nt] = (f32x4){0.f, 0.f, 0.f, 0.f};
    #pragma unroll
    for (int ch = 0; ch < 8; ++ch) {
      bf16x8 a[4], b[2];
      #pragma unroll
      for (int mt = 0; mt < 4; ++mt)
        a[mt] = *(const bf16x8*)&s_h2[(mt * 16 + l15) * H2S + ch * 32 + quad * 8];
      #pragma unroll
      for (int nt = 0; nt < 2; ++nt)
        b[nt] = *(const bf16x8*)&w2t[(size_t)(wave * 32 + nt * 16 + l15) * 256 + ch * 32 + quad * 8];
      #pragma unroll
      for (int mt = 0; mt < 4; ++mt)
        #pragma unroll
        for (int nt = 0; nt < 2; ++nt)
          acc2[mt][nt] = __builtin_amdgcn_mfma_f32_16x16x32_bf16(a[mt], b[nt], acc2[mt][nt], 0, 0, 0);
    }
    #pragma unroll
    for (int nt = 0; nt < 2; ++nt) {
      int col = wave * 32 + nt * 16 + l15;
      float bias = b2[col];
      #pragma unroll
      for (int mt = 0; mt < 4; ++mt)
        #pragma unroll
        for (int rg = 0; rg < 4; ++rg) {
          int row = mt * 16 + quad * 4 + rg;
          s_h1[row * H1S + col] = f2bf(geluf(acc2[mt][nt][rg] + bias));   // h3
        }
    }
  }
  __syncthreads();   // h3 visible; h2 reads done -> kern may overwrite region1

  // ---------- layer 3: 128 -> 32 linear (wave owns 16 rows) -> s_kern ----------
  {
    f32x4 acc3[2];
    acc3[0] = (f32x4){0.f, 0.f, 0.f, 0.f};
    acc3[1] = (f32x4){0.f, 0.f, 0.f, 0.f};
    #pragma unroll
    for (int ch = 0; ch < 4; ++ch) {
      bf16x8 a3 = *(const bf16x8*)&s_h1[(wave * 16 + l15) * H1S + ch * 32 + quad * 8];
      #pragma unroll
      for (int nt = 0; nt < 2; ++nt) {
        bf16x8 b3f = *(const bf16x8*)&w3t[(size_t)(nt * 16 + l15) * 128 + ch * 32 + quad * 8];
        acc3[nt] = __builtin_amdgcn_mfma_f32_16x16x32_bf16(a3, b3f, acc3[nt], 0, 0, 0);
      }
    }
    #pragma unroll
    for (int nt = 0; nt < 2; ++nt) {
      int col = nt * 16 + l15;
      float bias = b3[col];
      #pragma unroll
      for (int rg = 0; rg < 4; ++rg) {
        int row = wave * 16 + quad * 4 + rg;
        s_kern[row * KS + col] = acc3[nt][rg] + bias;
      }
    }
  }
  __syncthreads();

  // ---------- fused reduce ----------
  {
    const int xloc = tid >> 5;
    const int c    = tid & 31;
    float acc[TDIM] = {0.f, 0.f, 0.f, 0.f};
    const int ebase = xloc * 8;
    #pragma unroll
    for (int j = 0; j < KNBR; ++j) {
      float kv = s_kern[(ebase + j) * KS + c];
      int idx = nidx[e0 + ebase + j];
      const float* fp = f_y + (size_t)idx * CDIM + c;
      #pragma unroll
      for (int t = 0; t < TDIM; ++t)
        acc[t] += kv * fp[(size_t)t * N_Y * CDIM];
    }
    const int xg = blockIdx.x * 8 + xloc;
    #pragma unroll
    for (int t = 0; t < TDIM; ++t)
      out[((size_t)t * N_X + xg) * CDIM + c] = acc[t];
  }
}

extern "C" void kernel_launch(void* const* d_in, const int* in_sizes, int n_in,
                              void* d_out, int out_size, void* d_ws, size_t ws_size,
                              hipStream_t stream)
{
  const float* y   = (const float*)d_in[0];
  const float* x   = (const float*)d_in[1];
  const float* f_y = (const float*)d_in[2];
  const int*  nidx = (const int*)d_in[3];
  const float* W0 = (const float*)d_in[4];  const float* b0 = (const float*)d_in[5];
  const float* W1 = (const float*)d_in[6];  const float* b1 = (const float*)d_in[7];
  const float* W2 = (const float*)d_in[8];  const float* b2 = (const float*)d_in[9];
  const float* W3 = (const float*)d_in[10]; const float* b3 = (const float*)d_in[11];

  char* ws = (char*)d_ws;
  short* c_y  = (short*)(ws + 0);           // 50000*128*2  = 12,800,000
  float* c_x  = (float*)(ws + 12800000);    // 32768*128*4  = 16,777,216
  short* w1t  = (short*)(ws + 29577216);    // 256*128*2
  short* w2t  = (short*)(ws + 29642752);    // 128*256*2
  short* w3t  = (short*)(ws + 29708288);    //  32*128*2

  hipLaunchKernelGGL(prep_all, dim3(PREP_NB), dim3(256), 0, stream,
                     y, x, W0, b0, W1, W2, W3, w1t, w2t, w3t, c_y, c_x);
  hipLaunchKernelGGL(fused_edge, dim3(ECNT / 64), dim3(256), 0, stream,
                     c_y, c_x, nidx, f_y, w1t, b1, w2t, b2, w3t, b3, (float*)d_out);
}